// Round 5
// baseline (5875.280 us; speedup 1.0000x reference)
//
#include <hip/hip_runtime.h>
#include <cstdint>

// Instant-NGP hash encoding + 2-layer MLP, fully fused, all-fp32.
// N=524288 pts, L=16 levels, T=2^19 table, F=8 feats -> enc dim 128.
// Layer1: 128->128 + LeakyReLU(0.01). Layer2: 128->256.
//
// R4 changes vs R3:
//  - Single LDS buffer (enc reused for hidden) -> 17.3 KB/block -> 8 blocks/CU
//  - __launch_bounds__(256, 8) to pin VGPR <= 64 (full occupancy)
//  - Thread tile remap (px = t>>4, cy = t&15) + split column tile
//    {cy*4, 64+cy*4} so wave stores are fully-contiguous 256B segments
//    per point (kills write RMW amplification).

#define NPTS        524288
#define NLEVELS     16
#define TSIZE       (1u << 19)
#define TMASK       (TSIZE - 1u)
#define FFEAT       8
#define PTS_BLK     32          // points per block
#define PITCH       132         // 128 + 4 pad floats (breaks power-of-2 bank stride)

// floor(16 * 1.5^l) computed exactly; all values fp32-exact integers.
__constant__ float c_res[NLEVELS] = {
    16.f, 24.f, 36.f, 54.f, 81.f, 121.f, 182.f, 273.f,
    410.f, 615.f, 922.f, 1383.f, 2075.f, 3113.f, 4670.f, 7006.f
};

__global__ __launch_bounds__(256, 8)
void ngp_fused_kernel(const float* __restrict__ z,
                      const float* __restrict__ tables,
                      const float* __restrict__ W1,
                      const float* __restrict__ b1,
                      const float* __restrict__ W2,
                      const float* __restrict__ b2,
                      float* __restrict__ out)
{
    // Single shared buffer: holds encoding in Phase A/B, hidden in Phase B/C.
    __shared__ __align__(16) float buf[PTS_BLK][PITCH];
    __shared__ float zs[PTS_BLK * 3];

    const int t     = threadIdx.x;        // 0..255
    const int blk   = blockIdx.x;
    const int pbase = blk * PTS_BLK;

    // ---- stage z for this block's 32 points ----
    if (t < PTS_BLK * 3) {
        zs[t] = z[(size_t)pbase * 3 + t];
    }
    __syncthreads();

    // ---- Phase A: hash encoding. 32 pts x 16 levels = 512 tasks, 2/thread ----
    #pragma unroll
    for (int ti = 0; ti < 2; ++ti) {
        const int task = t + ti * 256;
        const int p = task & 31;       // point within block
        const int l = task >> 5;       // level 0..15

        const float res = c_res[l];
        const float xs0 = zs[p * 3 + 0] * res;
        const float xs1 = zs[p * 3 + 1] * res;
        const float xs2 = zs[p * 3 + 2] * res;
        const float f0 = floorf(xs0), f1 = floorf(xs1), f2 = floorf(xs2);
        const float w0 = xs0 - f0, w1 = xs1 - f1, w2 = xs2 - f2;
        const uint32_t x0 = (uint32_t)f0;
        const uint32_t x1 = (uint32_t)f1;
        const uint32_t x2 = (uint32_t)f2;

        const float* tab = tables + (size_t)l * (size_t)(TSIZE * FFEAT);

        float acc0 = 0.f, acc1 = 0.f, acc2 = 0.f, acc3 = 0.f;
        float acc4 = 0.f, acc5 = 0.f, acc6 = 0.f, acc7 = 0.f;

        #pragma unroll
        for (int c = 0; c < 8; ++c) {
            const uint32_t dx = (c >> 2) & 1u;   // dim0 bit (matches OFFS)
            const uint32_t dy = (c >> 1) & 1u;   // dim1 bit
            const uint32_t dz = c & 1u;          // dim2 bit

            // uint32 wraparound hash: primes {1, 2654435761, 805459861}
            const uint32_t hx = (x0 + dx) * 1u;
            const uint32_t hy = (x1 + dy) * 2654435761u;
            const uint32_t hz = (x2 + dz) * 805459861u;
            const uint32_t idx = (hx ^ hy ^ hz) & TMASK;

            const float4* fp = reinterpret_cast<const float4*>(tab + ((size_t)idx << 3));
            const float4 fa = fp[0];
            const float4 fb = fp[1];

            // trilinear weight, same multiply order as reference prod(-1)
            const float cwx = dx ? w0 : (1.0f - w0);
            const float cwy = dy ? w1 : (1.0f - w1);
            const float cwz = dz ? w2 : (1.0f - w2);
            const float cw = (cwx * cwy) * cwz;

            acc0 = fmaf(cw, fa.x, acc0);
            acc1 = fmaf(cw, fa.y, acc1);
            acc2 = fmaf(cw, fa.z, acc2);
            acc3 = fmaf(cw, fa.w, acc3);
            acc4 = fmaf(cw, fb.x, acc4);
            acc5 = fmaf(cw, fb.y, acc5);
            acc6 = fmaf(cw, fb.z, acc6);
            acc7 = fmaf(cw, fb.w, acc7);
        }

        float* e = &buf[p][l * FFEAT];
        reinterpret_cast<float4*>(e)[0] = make_float4(acc0, acc1, acc2, acc3);
        reinterpret_cast<float4*>(e)[1] = make_float4(acc4, acc5, acc6, acc7);
    }
    __syncthreads();

    // ---- Phase B: layer 1 (128 -> 128) + bias + LeakyReLU(0.01) ----
    // thread tile: 2 points (px, px+16) x 8 cols in split groups
    //   group 0: cols cy*4 .. cy*4+3
    //   group 1: cols 64+cy*4 .. 64+cy*4+3
    // -> wave stores cover contiguous 256B per point.
    const int px  = t >> 4;      // 0..15
    const int cy  = t & 15;      // 0..15
    const int ca  = cy * 4;      // group-0 col base
    const int cb  = 64 + cy * 4; // group-1 col base

    float h0[8], h1[8];
    {
        float a0[8], a1[8];
        #pragma unroll
        for (int j = 0; j < 8; ++j) { a0[j] = 0.f; a1[j] = 0.f; }

        #pragma unroll 2
        for (int k = 0; k < 128; k += 4) {
            const float4 e0 = *reinterpret_cast<const float4*>(&buf[px][k]);
            const float4 e1 = *reinterpret_cast<const float4*>(&buf[px + 16][k]);
            #pragma unroll
            for (int j = 0; j < 4; ++j) {
                const float4 wv = *reinterpret_cast<const float4*>(&W1[(size_t)(ca + j) * 128 + k]);
                a0[j] = fmaf(e0.x, wv.x, a0[j]);
                a0[j] = fmaf(e0.y, wv.y, a0[j]);
                a0[j] = fmaf(e0.z, wv.z, a0[j]);
                a0[j] = fmaf(e0.w, wv.w, a0[j]);
                a1[j] = fmaf(e1.x, wv.x, a1[j]);
                a1[j] = fmaf(e1.y, wv.y, a1[j]);
                a1[j] = fmaf(e1.z, wv.z, a1[j]);
                a1[j] = fmaf(e1.w, wv.w, a1[j]);
            }
            #pragma unroll
            for (int j = 0; j < 4; ++j) {
                const float4 wv = *reinterpret_cast<const float4*>(&W1[(size_t)(cb + j) * 128 + k]);
                a0[4 + j] = fmaf(e0.x, wv.x, a0[4 + j]);
                a0[4 + j] = fmaf(e0.y, wv.y, a0[4 + j]);
                a0[4 + j] = fmaf(e0.z, wv.z, a0[4 + j]);
                a0[4 + j] = fmaf(e0.w, wv.w, a0[4 + j]);
                a1[4 + j] = fmaf(e1.x, wv.x, a1[4 + j]);
                a1[4 + j] = fmaf(e1.y, wv.y, a1[4 + j]);
                a1[4 + j] = fmaf(e1.z, wv.z, a1[4 + j]);
                a1[4 + j] = fmaf(e1.w, wv.w, a1[4 + j]);
            }
        }

        #pragma unroll
        for (int j = 0; j < 8; ++j) {
            const int col = (j < 4) ? (ca + j) : (cb + j - 4);
            const float bj = b1[col];
            float v0 = a0[j] + bj;
            float v1 = a1[j] + bj;
            h0[j] = (v0 >= 0.f) ? v0 : 0.01f * v0;
            h1[j] = (v1 >= 0.f) ? v1 : 0.01f * v1;
        }
    }
    __syncthreads();   // all reads of encoding done -> safe to overwrite buf

    // write hidden into the SAME buffer
    *reinterpret_cast<float4*>(&buf[px][ca])      = make_float4(h0[0], h0[1], h0[2], h0[3]);
    *reinterpret_cast<float4*>(&buf[px][cb])      = make_float4(h0[4], h0[5], h0[6], h0[7]);
    *reinterpret_cast<float4*>(&buf[px + 16][ca]) = make_float4(h1[0], h1[1], h1[2], h1[3]);
    *reinterpret_cast<float4*>(&buf[px + 16][cb]) = make_float4(h1[4], h1[5], h1[6], h1[7]);
    __syncthreads();

    // ---- Phase C: layer 2 (128 -> 256) + bias, write output ----
    #pragma unroll
    for (int half = 0; half < 2; ++half) {
        float c0[8], c1[8];
        #pragma unroll
        for (int j = 0; j < 8; ++j) { c0[j] = 0.f; c1[j] = 0.f; }

        const int oca = half * 128 + ca;   // group-0 output cols
        const int ocb = half * 128 + cb;   // group-1 output cols

        #pragma unroll 2
        for (int k = 0; k < 128; k += 4) {
            const float4 g0 = *reinterpret_cast<const float4*>(&buf[px][k]);
            const float4 g1 = *reinterpret_cast<const float4*>(&buf[px + 16][k]);
            #pragma unroll
            for (int j = 0; j < 4; ++j) {
                const float4 wv = *reinterpret_cast<const float4*>(&W2[(size_t)(oca + j) * 128 + k]);
                c0[j] = fmaf(g0.x, wv.x, c0[j]);
                c0[j] = fmaf(g0.y, wv.y, c0[j]);
                c0[j] = fmaf(g0.z, wv.z, c0[j]);
                c0[j] = fmaf(g0.w, wv.w, c0[j]);
                c1[j] = fmaf(g1.x, wv.x, c1[j]);
                c1[j] = fmaf(g1.y, wv.y, c1[j]);
                c1[j] = fmaf(g1.z, wv.z, c1[j]);
                c1[j] = fmaf(g1.w, wv.w, c1[j]);
            }
            #pragma unroll
            for (int j = 0; j < 4; ++j) {
                const float4 wv = *reinterpret_cast<const float4*>(&W2[(size_t)(ocb + j) * 128 + k]);
                c0[4 + j] = fmaf(g0.x, wv.x, c0[4 + j]);
                c0[4 + j] = fmaf(g0.y, wv.y, c0[4 + j]);
                c0[4 + j] = fmaf(g0.z, wv.z, c0[4 + j]);
                c0[4 + j] = fmaf(g0.w, wv.w, c0[4 + j]);
                c1[4 + j] = fmaf(g1.x, wv.x, c1[4 + j]);
                c1[4 + j] = fmaf(g1.y, wv.y, c1[4 + j]);
                c1[4 + j] = fmaf(g1.z, wv.z, c1[4 + j]);
                c1[4 + j] = fmaf(g1.w, wv.w, c1[4 + j]);
            }
        }

        #pragma unroll
        for (int j = 0; j < 4; ++j) {
            c0[j]     += b2[oca + j];
            c1[j]     += b2[oca + j];
            c0[4 + j] += b2[ocb + j];
            c1[4 + j] += b2[ocb + j];
        }

        // Coalesced stores: per store instruction, 16 lanes (one px) cover a
        // contiguous 256B segment of one point's row.
        float* o0 = out + (size_t)(pbase + px) * 256 + half * 128;
        float* o1 = out + (size_t)(pbase + px + 16) * 256 + half * 128;
        *reinterpret_cast<float4*>(o0 + ca) = make_float4(c0[0], c0[1], c0[2], c0[3]);
        *reinterpret_cast<float4*>(o0 + cb) = make_float4(c0[4], c0[5], c0[6], c0[7]);
        *reinterpret_cast<float4*>(o1 + ca) = make_float4(c1[0], c1[1], c1[2], c1[3]);
        *reinterpret_cast<float4*>(o1 + cb) = make_float4(c1[4], c1[5], c1[6], c1[7]);
    }
}

extern "C" void kernel_launch(void* const* d_in, const int* in_sizes, int n_in,
                              void* d_out, int out_size, void* d_ws, size_t ws_size,
                              hipStream_t stream) {
    (void)in_sizes; (void)n_in; (void)d_ws; (void)ws_size; (void)out_size;

    const float* z      = (const float*)d_in[0];   // [524288, 3]
    const float* tables = (const float*)d_in[1];   // [16, 2^19, 8]
    const float* W1     = (const float*)d_in[2];   // [128, 128]
    const float* b1     = (const float*)d_in[3];   // [128]
    const float* W2     = (const float*)d_in[4];   // [256, 128]
    const float* b2     = (const float*)d_in[5];   // [256]
    float* out          = (float*)d_out;           // [524288, 256]

    const int nblocks = NPTS / PTS_BLK;            // 16384
    ngp_fused_kernel<<<dim3(nblocks), dim3(256), 0, stream>>>(
        z, tables, W1, b1, W2, b2, out);
}

// Round 7
// 5754.419 us; speedup vs baseline: 1.0210x; 1.0210x over previous
//
#include <hip/hip_runtime.h>
#include <cstdint>

// Instant-NGP hash encoding + 2-layer MLP, fully fused, all-fp32.
// N=524288 pts, L=16 levels, T=2^19 table, F=8 feats -> enc dim 128.
// Layer1: 128->128 + LeakyReLU(0.01). Layer2: 128->256.
//
// R6 = R5 with the compile fix: __builtin_nontemporal_store needs a native
// clang vector type, not HIP's float4 class. Everything else unchanged:
//  - __launch_bounds__(256, 4): (256,8) forced VGPR 64->32 -> scratch spills
//  - single LDS buffer 17.4KB, split-column coalesced stores (no write RMW)
//  - NT output stores so the 512MB stream doesn't evict 256MB tables from L3

#define NPTS        524288
#define NLEVELS     16
#define TSIZE       (1u << 19)
#define TMASK       (TSIZE - 1u)
#define FFEAT       8
#define PTS_BLK     32          // points per block
#define PITCH       132         // 128 + 4 pad floats (breaks power-of-2 bank stride)

typedef float v4f __attribute__((ext_vector_type(4)));   // native vector for NT stores

// floor(16 * 1.5^l) computed exactly; all values fp32-exact integers.
__constant__ float c_res[NLEVELS] = {
    16.f, 24.f, 36.f, 54.f, 81.f, 121.f, 182.f, 273.f,
    410.f, 615.f, 922.f, 1383.f, 2075.f, 3113.f, 4670.f, 7006.f
};

__global__ __launch_bounds__(256, 4)
void ngp_fused_kernel(const float* __restrict__ z,
                      const float* __restrict__ tables,
                      const float* __restrict__ W1,
                      const float* __restrict__ b1,
                      const float* __restrict__ W2,
                      const float* __restrict__ b2,
                      float* __restrict__ out)
{
    // Single shared buffer: holds encoding in Phase A/B, hidden in Phase B/C.
    __shared__ __align__(16) float buf[PTS_BLK][PITCH];
    __shared__ float zs[PTS_BLK * 3];

    const int t     = threadIdx.x;        // 0..255
    const int blk   = blockIdx.x;
    const int pbase = blk * PTS_BLK;

    // ---- stage z for this block's 32 points ----
    if (t < PTS_BLK * 3) {
        zs[t] = z[(size_t)pbase * 3 + t];
    }
    __syncthreads();

    // ---- Phase A: hash encoding. 32 pts x 16 levels = 512 tasks, 2/thread ----
    #pragma unroll
    for (int ti = 0; ti < 2; ++ti) {
        const int task = t + ti * 256;
        const int p = task & 31;       // point within block
        const int l = task >> 5;       // level 0..15

        const float res = c_res[l];
        const float xs0 = zs[p * 3 + 0] * res;
        const float xs1 = zs[p * 3 + 1] * res;
        const float xs2 = zs[p * 3 + 2] * res;
        const float f0 = floorf(xs0), f1 = floorf(xs1), f2 = floorf(xs2);
        const float w0 = xs0 - f0, w1 = xs1 - f1, w2 = xs2 - f2;
        const uint32_t x0 = (uint32_t)f0;
        const uint32_t x1 = (uint32_t)f1;
        const uint32_t x2 = (uint32_t)f2;

        const float* tab = tables + (size_t)l * (size_t)(TSIZE * FFEAT);

        float acc0 = 0.f, acc1 = 0.f, acc2 = 0.f, acc3 = 0.f;
        float acc4 = 0.f, acc5 = 0.f, acc6 = 0.f, acc7 = 0.f;

        #pragma unroll
        for (int c = 0; c < 8; ++c) {
            const uint32_t dx = (c >> 2) & 1u;   // dim0 bit (matches OFFS)
            const uint32_t dy = (c >> 1) & 1u;   // dim1 bit
            const uint32_t dz = c & 1u;          // dim2 bit

            // uint32 wraparound hash: primes {1, 2654435761, 805459861}
            const uint32_t hx = (x0 + dx) * 1u;
            const uint32_t hy = (x1 + dy) * 2654435761u;
            const uint32_t hz = (x2 + dz) * 805459861u;
            const uint32_t idx = (hx ^ hy ^ hz) & TMASK;

            const float4* fp = reinterpret_cast<const float4*>(tab + ((size_t)idx << 3));
            const float4 fa = fp[0];
            const float4 fb = fp[1];

            // trilinear weight, same multiply order as reference prod(-1)
            const float cwx = dx ? w0 : (1.0f - w0);
            const float cwy = dy ? w1 : (1.0f - w1);
            const float cwz = dz ? w2 : (1.0f - w2);
            const float cw = (cwx * cwy) * cwz;

            acc0 = fmaf(cw, fa.x, acc0);
            acc1 = fmaf(cw, fa.y, acc1);
            acc2 = fmaf(cw, fa.z, acc2);
            acc3 = fmaf(cw, fa.w, acc3);
            acc4 = fmaf(cw, fb.x, acc4);
            acc5 = fmaf(cw, fb.y, acc5);
            acc6 = fmaf(cw, fb.z, acc6);
            acc7 = fmaf(cw, fb.w, acc7);
        }

        float* e = &buf[p][l * FFEAT];
        reinterpret_cast<float4*>(e)[0] = make_float4(acc0, acc1, acc2, acc3);
        reinterpret_cast<float4*>(e)[1] = make_float4(acc4, acc5, acc6, acc7);
    }
    __syncthreads();

    // ---- Phase B: layer 1 (128 -> 128) + bias + LeakyReLU(0.01) ----
    // thread tile: 2 points (px, px+16) x 8 cols in split groups
    //   group 0: cols cy*4 .. cy*4+3
    //   group 1: cols 64+cy*4 .. 64+cy*4+3
    const int px  = t >> 4;      // 0..15
    const int cy  = t & 15;      // 0..15
    const int ca  = cy * 4;      // group-0 col base
    const int cb  = 64 + cy * 4; // group-1 col base

    float h0[8], h1[8];
    {
        float a0[8], a1[8];
        #pragma unroll
        for (int j = 0; j < 8; ++j) { a0[j] = 0.f; a1[j] = 0.f; }

        #pragma unroll 2
        for (int k = 0; k < 128; k += 4) {
            const float4 e0 = *reinterpret_cast<const float4*>(&buf[px][k]);
            const float4 e1 = *reinterpret_cast<const float4*>(&buf[px + 16][k]);
            #pragma unroll
            for (int j = 0; j < 4; ++j) {
                const float4 wv = *reinterpret_cast<const float4*>(&W1[(size_t)(ca + j) * 128 + k]);
                a0[j] = fmaf(e0.x, wv.x, a0[j]);
                a0[j] = fmaf(e0.y, wv.y, a0[j]);
                a0[j] = fmaf(e0.z, wv.z, a0[j]);
                a0[j] = fmaf(e0.w, wv.w, a0[j]);
                a1[j] = fmaf(e1.x, wv.x, a1[j]);
                a1[j] = fmaf(e1.y, wv.y, a1[j]);
                a1[j] = fmaf(e1.z, wv.z, a1[j]);
                a1[j] = fmaf(e1.w, wv.w, a1[j]);
            }
            #pragma unroll
            for (int j = 0; j < 4; ++j) {
                const float4 wv = *reinterpret_cast<const float4*>(&W1[(size_t)(cb + j) * 128 + k]);
                a0[4 + j] = fmaf(e0.x, wv.x, a0[4 + j]);
                a0[4 + j] = fmaf(e0.y, wv.y, a0[4 + j]);
                a0[4 + j] = fmaf(e0.z, wv.z, a0[4 + j]);
                a0[4 + j] = fmaf(e0.w, wv.w, a0[4 + j]);
                a1[4 + j] = fmaf(e1.x, wv.x, a1[4 + j]);
                a1[4 + j] = fmaf(e1.y, wv.y, a1[4 + j]);
                a1[4 + j] = fmaf(e1.z, wv.z, a1[4 + j]);
                a1[4 + j] = fmaf(e1.w, wv.w, a1[4 + j]);
            }
        }

        #pragma unroll
        for (int j = 0; j < 8; ++j) {
            const int col = (j < 4) ? (ca + j) : (cb + j - 4);
            const float bj = b1[col];
            float v0 = a0[j] + bj;
            float v1 = a1[j] + bj;
            h0[j] = (v0 >= 0.f) ? v0 : 0.01f * v0;
            h1[j] = (v1 >= 0.f) ? v1 : 0.01f * v1;
        }
    }
    __syncthreads();   // all reads of encoding done -> safe to overwrite buf

    // write hidden into the SAME buffer
    *reinterpret_cast<float4*>(&buf[px][ca])      = make_float4(h0[0], h0[1], h0[2], h0[3]);
    *reinterpret_cast<float4*>(&buf[px][cb])      = make_float4(h0[4], h0[5], h0[6], h0[7]);
    *reinterpret_cast<float4*>(&buf[px + 16][ca]) = make_float4(h1[0], h1[1], h1[2], h1[3]);
    *reinterpret_cast<float4*>(&buf[px + 16][cb]) = make_float4(h1[4], h1[5], h1[6], h1[7]);
    __syncthreads();

    // ---- Phase C: layer 2 (128 -> 256) + bias, write output ----
    #pragma unroll
    for (int half = 0; half < 2; ++half) {
        float c0[8], c1[8];
        #pragma unroll
        for (int j = 0; j < 8; ++j) { c0[j] = 0.f; c1[j] = 0.f; }

        const int oca = half * 128 + ca;   // group-0 output cols
        const int ocb = half * 128 + cb;   // group-1 output cols

        #pragma unroll 2
        for (int k = 0; k < 128; k += 4) {
            const float4 g0 = *reinterpret_cast<const float4*>(&buf[px][k]);
            const float4 g1 = *reinterpret_cast<const float4*>(&buf[px + 16][k]);
            #pragma unroll
            for (int j = 0; j < 4; ++j) {
                const float4 wv = *reinterpret_cast<const float4*>(&W2[(size_t)(oca + j) * 128 + k]);
                c0[j] = fmaf(g0.x, wv.x, c0[j]);
                c0[j] = fmaf(g0.y, wv.y, c0[j]);
                c0[j] = fmaf(g0.z, wv.z, c0[j]);
                c0[j] = fmaf(g0.w, wv.w, c0[j]);
                c1[j] = fmaf(g1.x, wv.x, c1[j]);
                c1[j] = fmaf(g1.y, wv.y, c1[j]);
                c1[j] = fmaf(g1.z, wv.z, c1[j]);
                c1[j] = fmaf(g1.w, wv.w, c1[j]);
            }
            #pragma unroll
            for (int j = 0; j < 4; ++j) {
                const float4 wv = *reinterpret_cast<const float4*>(&W2[(size_t)(ocb + j) * 128 + k]);
                c0[4 + j] = fmaf(g0.x, wv.x, c0[4 + j]);
                c0[4 + j] = fmaf(g0.y, wv.y, c0[4 + j]);
                c0[4 + j] = fmaf(g0.z, wv.z, c0[4 + j]);
                c0[4 + j] = fmaf(g0.w, wv.w, c0[4 + j]);
                c1[4 + j] = fmaf(g1.x, wv.x, c1[4 + j]);
                c1[4 + j] = fmaf(g1.y, wv.y, c1[4 + j]);
                c1[4 + j] = fmaf(g1.z, wv.z, c1[4 + j]);
                c1[4 + j] = fmaf(g1.w, wv.w, c1[4 + j]);
            }
        }

        #pragma unroll
        for (int j = 0; j < 4; ++j) {
            c0[j]     += b2[oca + j];
            c1[j]     += b2[oca + j];
            c0[4 + j] += b2[ocb + j];
            c1[4 + j] += b2[ocb + j];
        }

        // Coalesced nontemporal stores: per instruction, each 16-lane group
        // covers a contiguous 256B segment of one point's row; NT keeps the
        // 512MB output stream from evicting the 256MB tables out of L3.
        float* o0 = out + (size_t)(pbase + px) * 256 + half * 128;
        float* o1 = out + (size_t)(pbase + px + 16) * 256 + half * 128;
        v4f s;
        s.x = c0[0]; s.y = c0[1]; s.z = c0[2]; s.w = c0[3];
        __builtin_nontemporal_store(s, reinterpret_cast<v4f*>(o0 + ca));
        s.x = c0[4]; s.y = c0[5]; s.z = c0[6]; s.w = c0[7];
        __builtin_nontemporal_store(s, reinterpret_cast<v4f*>(o0 + cb));
        s.x = c1[0]; s.y = c1[1]; s.z = c1[2]; s.w = c1[3];
        __builtin_nontemporal_store(s, reinterpret_cast<v4f*>(o1 + ca));
        s.x = c1[4]; s.y = c1[5]; s.z = c1[6]; s.w = c1[7];
        __builtin_nontemporal_store(s, reinterpret_cast<v4f*>(o1 + cb));
    }
}

extern "C" void kernel_launch(void* const* d_in, const int* in_sizes, int n_in,
                              void* d_out, int out_size, void* d_ws, size_t ws_size,
                              hipStream_t stream) {
    (void)in_sizes; (void)n_in; (void)d_ws; (void)ws_size; (void)out_size;

    const float* z      = (const float*)d_in[0];   // [524288, 3]
    const float* tables = (const float*)d_in[1];   // [16, 2^19, 8]
    const float* W1     = (const float*)d_in[2];   // [128, 128]
    const float* b1     = (const float*)d_in[3];   // [128]
    const float* W2     = (const float*)d_in[4];   // [256, 128]
    const float* b2     = (const float*)d_in[5];   // [256]
    float* out          = (float*)d_out;           // [524288, 256]

    const int nblocks = NPTS / PTS_BLK;            // 16384
    ngp_fused_kernel<<<dim3(nblocks), dim3(256), 0, stream>>>(
        z, tables, W1, b1, W2, b2, out);
}

// Round 8
// 1949.446 us; speedup vs baseline: 3.0138x; 2.9518x over previous
//
#include <hip/hip_runtime.h>
#include <cstdint>

// Instant-NGP hash encoding + 2-layer MLP, fully fused, all-fp32.
// N=524288 pts, L=16 levels, T=2^19 table, F=8 feats -> enc dim 128.
// Layer1: 128->128 + LeakyReLU(0.01). Layer2: 128->256.
//
// R7 changes (evidence: R3=2637us broadcast-W; R6=5900us scatter-W):
//  - Revert Phase B/C thread map to R3 style (px=t&15, cy=t>>4, 8 contig
//    cols): W-loads are 4 distinct lines/wave-instr (16-lane broadcast),
//    4x less L1 scatter than R6's 16-line pattern (3.1GB vs 12.6GB total).
//  - Output staged through LDS (sout) so global stores are contiguous
//    512B-per-32-lane NT stores: keeps R4/R6's WRITE=ideal (no RMW).
//  - __launch_bounds__(256,6): probe whether the 48% occupancy at VGPR=64
//    was the ',4' attribute capping waves/EU. 512/6=85 VGPR budget >= 64,
//    so no spill risk either way.

#define NPTS        524288
#define NLEVELS     16
#define TSIZE       (1u << 19)
#define TMASK       (TSIZE - 1u)
#define FFEAT       8
#define PTS_BLK     32          // points per block
#define PITCH       132         // 128 + 4 pad floats (breaks power-of-2 bank stride)

typedef float v4f __attribute__((ext_vector_type(4)));   // native vector for NT stores

// floor(16 * 1.5^l) computed exactly; all values fp32-exact integers.
__constant__ float c_res[NLEVELS] = {
    16.f, 24.f, 36.f, 54.f, 81.f, 121.f, 182.f, 273.f,
    410.f, 615.f, 922.f, 1383.f, 2075.f, 3113.f, 4670.f, 7006.f
};

__global__ __launch_bounds__(256, 6)
void ngp_fused_kernel(const float* __restrict__ z,
                      const float* __restrict__ tables,
                      const float* __restrict__ W1,
                      const float* __restrict__ b1,
                      const float* __restrict__ W2,
                      const float* __restrict__ b2,
                      float* __restrict__ out)
{
    __shared__ __align__(16) float buf[PTS_BLK][PITCH];    // enc, then hidden
    __shared__ __align__(16) float sout[PTS_BLK][PITCH];   // output staging
    __shared__ float zs[PTS_BLK * 3];

    const int t     = threadIdx.x;        // 0..255
    const int blk   = blockIdx.x;
    const int pbase = blk * PTS_BLK;

    // ---- stage z for this block's 32 points ----
    if (t < PTS_BLK * 3) {
        zs[t] = z[(size_t)pbase * 3 + t];
    }
    __syncthreads();

    // ---- Phase A: hash encoding. 32 pts x 16 levels = 512 tasks, 2/thread ----
    #pragma unroll
    for (int ti = 0; ti < 2; ++ti) {
        const int task = t + ti * 256;
        const int p = task & 31;       // point within block
        const int l = task >> 5;       // level 0..15

        const float res = c_res[l];
        const float xs0 = zs[p * 3 + 0] * res;
        const float xs1 = zs[p * 3 + 1] * res;
        const float xs2 = zs[p * 3 + 2] * res;
        const float f0 = floorf(xs0), f1 = floorf(xs1), f2 = floorf(xs2);
        const float w0 = xs0 - f0, w1 = xs1 - f1, w2 = xs2 - f2;
        const uint32_t x0 = (uint32_t)f0;
        const uint32_t x1 = (uint32_t)f1;
        const uint32_t x2 = (uint32_t)f2;

        const float* tab = tables + (size_t)l * (size_t)(TSIZE * FFEAT);

        float acc0 = 0.f, acc1 = 0.f, acc2 = 0.f, acc3 = 0.f;
        float acc4 = 0.f, acc5 = 0.f, acc6 = 0.f, acc7 = 0.f;

        #pragma unroll
        for (int c = 0; c < 8; ++c) {
            const uint32_t dx = (c >> 2) & 1u;   // dim0 bit (matches OFFS)
            const uint32_t dy = (c >> 1) & 1u;   // dim1 bit
            const uint32_t dz = c & 1u;          // dim2 bit

            // uint32 wraparound hash: primes {1, 2654435761, 805459861}
            const uint32_t hx = (x0 + dx) * 1u;
            const uint32_t hy = (x1 + dy) * 2654435761u;
            const uint32_t hz = (x2 + dz) * 805459861u;
            const uint32_t idx = (hx ^ hy ^ hz) & TMASK;

            const float4* fp = reinterpret_cast<const float4*>(tab + ((size_t)idx << 3));
            const float4 fa = fp[0];
            const float4 fb = fp[1];

            // trilinear weight, same multiply order as reference prod(-1)
            const float cwx = dx ? w0 : (1.0f - w0);
            const float cwy = dy ? w1 : (1.0f - w1);
            const float cwz = dz ? w2 : (1.0f - w2);
            const float cw = (cwx * cwy) * cwz;

            acc0 = fmaf(cw, fa.x, acc0);
            acc1 = fmaf(cw, fa.y, acc1);
            acc2 = fmaf(cw, fa.z, acc2);
            acc3 = fmaf(cw, fa.w, acc3);
            acc4 = fmaf(cw, fb.x, acc4);
            acc5 = fmaf(cw, fb.y, acc5);
            acc6 = fmaf(cw, fb.z, acc6);
            acc7 = fmaf(cw, fb.w, acc7);
        }

        float* e = &buf[p][l * FFEAT];
        reinterpret_cast<float4*>(e)[0] = make_float4(acc0, acc1, acc2, acc3);
        reinterpret_cast<float4*>(e)[1] = make_float4(acc4, acc5, acc6, acc7);
    }
    __syncthreads();

    // ---- Phase B: layer 1 (128 -> 128) + bias + LeakyReLU(0.01) ----
    // R3 mapping: thread = 2 points (px, px+16) x 8 contiguous cols.
    // Per wave-instr, W1 address depends only on cy (t>>4): 4 distinct
    // lines, 16-lane broadcast -> minimal L1 scatter.
    const int px   = t & 15;     // 0..15
    const int cy   = t >> 4;     // 0..15
    const int colb = cy * 8;

    float h0[8], h1[8];
    {
        float a0[8], a1[8];
        #pragma unroll
        for (int j = 0; j < 8; ++j) { a0[j] = 0.f; a1[j] = 0.f; }

        #pragma unroll 2
        for (int k = 0; k < 128; k += 4) {
            const float4 e0 = *reinterpret_cast<const float4*>(&buf[px][k]);
            const float4 e1 = *reinterpret_cast<const float4*>(&buf[px + 16][k]);
            #pragma unroll
            for (int j = 0; j < 8; ++j) {
                const float4 wv = *reinterpret_cast<const float4*>(&W1[(size_t)(colb + j) * 128 + k]);
                a0[j] = fmaf(e0.x, wv.x, a0[j]);
                a0[j] = fmaf(e0.y, wv.y, a0[j]);
                a0[j] = fmaf(e0.z, wv.z, a0[j]);
                a0[j] = fmaf(e0.w, wv.w, a0[j]);
                a1[j] = fmaf(e1.x, wv.x, a1[j]);
                a1[j] = fmaf(e1.y, wv.y, a1[j]);
                a1[j] = fmaf(e1.z, wv.z, a1[j]);
                a1[j] = fmaf(e1.w, wv.w, a1[j]);
            }
        }

        #pragma unroll
        for (int j = 0; j < 8; ++j) {
            const float bj = b1[colb + j];
            float v0 = a0[j] + bj;
            float v1 = a1[j] + bj;
            h0[j] = (v0 >= 0.f) ? v0 : 0.01f * v0;
            h1[j] = (v1 >= 0.f) ? v1 : 0.01f * v1;
        }
    }
    __syncthreads();   // all reads of encoding done -> safe to overwrite buf

    // write hidden into the SAME buffer
    *reinterpret_cast<float4*>(&buf[px][colb])          = make_float4(h0[0], h0[1], h0[2], h0[3]);
    *reinterpret_cast<float4*>(&buf[px][colb + 4])      = make_float4(h0[4], h0[5], h0[6], h0[7]);
    *reinterpret_cast<float4*>(&buf[px + 16][colb])     = make_float4(h1[0], h1[1], h1[2], h1[3]);
    *reinterpret_cast<float4*>(&buf[px + 16][colb + 4]) = make_float4(h1[4], h1[5], h1[6], h1[7]);
    __syncthreads();

    // ---- Phase C: layer 2 (128 -> 256) + bias; stage each 128-col half
    //      through LDS, then contiguous NT stores ----
    #pragma unroll
    for (int half = 0; half < 2; ++half) {
        float c0[8], c1[8];
        #pragma unroll
        for (int j = 0; j < 8; ++j) { c0[j] = 0.f; c1[j] = 0.f; }

        const int orow = half * 128 + colb;   // W2 row base for this thread

        #pragma unroll 2
        for (int k = 0; k < 128; k += 4) {
            const float4 g0 = *reinterpret_cast<const float4*>(&buf[px][k]);
            const float4 g1 = *reinterpret_cast<const float4*>(&buf[px + 16][k]);
            #pragma unroll
            for (int j = 0; j < 8; ++j) {
                const float4 wv = *reinterpret_cast<const float4*>(&W2[(size_t)(orow + j) * 128 + k]);
                c0[j] = fmaf(g0.x, wv.x, c0[j]);
                c0[j] = fmaf(g0.y, wv.y, c0[j]);
                c0[j] = fmaf(g0.z, wv.z, c0[j]);
                c0[j] = fmaf(g0.w, wv.w, c0[j]);
                c1[j] = fmaf(g1.x, wv.x, c1[j]);
                c1[j] = fmaf(g1.y, wv.y, c1[j]);
                c1[j] = fmaf(g1.z, wv.z, c1[j]);
                c1[j] = fmaf(g1.w, wv.w, c1[j]);
            }
        }

        #pragma unroll
        for (int j = 0; j < 8; ++j) {
            const float bj = b2[orow + j];
            c0[j] += bj;
            c1[j] += bj;
        }

        // stage this half's [32 pts][128 cols] tile in LDS
        *reinterpret_cast<float4*>(&sout[px][colb])          = make_float4(c0[0], c0[1], c0[2], c0[3]);
        *reinterpret_cast<float4*>(&sout[px][colb + 4])      = make_float4(c0[4], c0[5], c0[6], c0[7]);
        *reinterpret_cast<float4*>(&sout[px + 16][colb])     = make_float4(c1[0], c1[1], c1[2], c1[3]);
        *reinterpret_cast<float4*>(&sout[px + 16][colb + 4]) = make_float4(c1[4], c1[5], c1[6], c1[7]);
        __syncthreads();

        // copy out: 1024 float4s; consecutive threads -> consecutive 16B,
        // each 32-lane group covers one point's contiguous 512B segment.
        #pragma unroll
        for (int i = 0; i < 4; ++i) {
            const int idx = t + i * 256;
            const int p   = idx >> 5;       // 0..31
            const int c4  = idx & 31;       // float4 index within 128 cols
            const float4 v = *reinterpret_cast<const float4*>(&sout[p][c4 * 4]);
            v4f s; s.x = v.x; s.y = v.y; s.z = v.z; s.w = v.w;
            __builtin_nontemporal_store(
                s, reinterpret_cast<v4f*>(out + (size_t)(pbase + p) * 256 + half * 128 + c4 * 4));
        }
        __syncthreads();   // protect sout before next half overwrites it
    }
}

extern "C" void kernel_launch(void* const* d_in, const int* in_sizes, int n_in,
                              void* d_out, int out_size, void* d_ws, size_t ws_size,
                              hipStream_t stream) {
    (void)in_sizes; (void)n_in; (void)d_ws; (void)ws_size; (void)out_size;

    const float* z      = (const float*)d_in[0];   // [524288, 3]
    const float* tables = (const float*)d_in[1];   // [16, 2^19, 8]
    const float* W1     = (const float*)d_in[2];   // [128, 128]
    const float* b1     = (const float*)d_in[3];   // [128]
    const float* W2     = (const float*)d_in[4];   // [256, 128]
    const float* b2     = (const float*)d_in[5];   // [256]
    float* out          = (float*)d_out;           // [524288, 256]

    const int nblocks = NPTS / PTS_BLK;            // 16384
    ngp_fused_kernel<<<dim3(nblocks), dim3(256), 0, stream>>>(
        z, tables, W1, b1, W2, b2, out);
}